// Round 2
// baseline (833.765 us; speedup 1.0000x reference)
//
#include <hip/hip_runtime.h>

#define T_STEPS 800
#define NBATCH  32
#define SST     1024
#define ROW     5120   // SST * 5

#define SCAN_BLOCKS 64
#define COPY_BLOCKS 1536
#define GRID (SCAN_BLOCKS + COPY_BLOCKS)

__device__ __forceinline__ float lse5(float v0, float v1, float v2, float v3, float v4) {
  float m = fmaxf(fmaxf(fmaxf(v0, v1), fmaxf(v2, v3)), v4);
  float s = __expf(v0 - m) + __expf(v1 - m) + __expf(v2 - m) +
            __expf(v3 - m) + __expf(v4 - m);
  return m + __logf(s);
}

// Raw barrier: LDS fence only, leaves global prefetch (vmcnt) in flight.
__device__ __forceinline__ void sync_lds() {
  asm volatile("s_waitcnt lgkmcnt(0)" ::: "memory");
  __builtin_amdgcn_s_barrier();
  asm volatile("" ::: "memory");
}

// Per-thread score prefetch for one step: 20 contiguous floats at 20u
// (5x dwordx4), plus (bwd only) the 4 scattered self-scores.
template <int DIR>
__device__ __forceinline__ void prefetch(const float* __restrict__ base, int step, int u,
                                         float* __restrict__ r, float* __restrict__ s) {
  const int t = DIR ? (T_STEPS - 1 - step) : step;
  const float* rp = base + (size_t)t * (NBATCH * ROW);
#pragma unroll
  for (int m = 0; m < 5; ++m)
    *(float4*)&r[4 * m] = *(const float4*)&rp[20 * u + 4 * m];
  if (DIR) {
#pragma unroll
    for (int j = 0; j < 4; ++j) s[j] = rp[5 * u + 1280 * j];
  }
}

// DIR=0 (fwd): thread u owns states {4u..4u+3}. Gather: abuf[u + 256k].
// DIR=1 (bwd): thread u owns states {u + 256j}. Gather: abuf[4u..4u+3].
template <int DIR>
__device__ void scan_run(const float* __restrict__ scores, float* __restrict__ out,
                         int n, float (*abuf)[SST]) {
  const int u = threadIdx.x;  // 0..255
  const float* base = scores + (size_t)n * ROW;
  float* outn = out + (size_t)n * (T_STEPS + 1) * SST;

  float a[4] = {0.f, 0.f, 0.f, 0.f};  // own states' alpha/beta (self-edge operand)

  // 4-deep register prefetch pipeline (steps 0..3)
  float v[4][20];
  float s5[4][4];
#pragma unroll
  for (int i = 0; i < 4; ++i) prefetch<DIR>(base, i, u, v[i], s5[i]);

  // init alpha[0]=0 / beta[T]=0 in LDS and in the output
  abuf[0][u] = 0.f; abuf[0][u + 256] = 0.f; abuf[0][u + 512] = 0.f; abuf[0][u + 768] = 0.f;
  {
    const float4 z = {0.f, 0.f, 0.f, 0.f};
    const size_t t0 = DIR ? (size_t)T_STEPS : 0;
    ((float4*)(outn + t0 * SST))[u] = z;
  }
  sync_lds();

  for (int p = 0; p < T_STEPS; p += 4) {
#pragma unroll
    for (int i = 0; i < 4; ++i) {
      const int step = p + i;
      const int cur = step & 1;
      const int nxt = cur ^ 1;

      float4 pv;
      if (DIR == 0) {
        pv.x = abuf[cur][u];
        pv.y = abuf[cur][u + 256];
        pv.z = abuf[cur][u + 512];
        pv.w = abuf[cur][u + 768];
      } else {
        pv = *(const float4*)&abuf[cur][4 * u];
      }

      float na[4];
#pragma unroll
      for (int j = 0; j < 4; ++j) {
        float v0, v1, v2, v3, v4;
        if (DIR == 0) {
          // state 4u+j: its 5 scores are flat [5j..5j+4] of this thread's 20
          v0 = v[i][5 * j + 0] + a[j];
          v1 = v[i][5 * j + 1] + pv.x;
          v2 = v[i][5 * j + 2] + pv.y;
          v3 = v[i][5 * j + 3] + pv.z;
          v4 = v[i][5 * j + 4] + pv.w;
        } else {
          // state u+256j: self score scattered; trans scores at flat 1+j+5m
          v0 = s5[i][j]          + a[j];
          v1 = v[i][1 + j + 0]   + pv.x;
          v2 = v[i][1 + j + 5]   + pv.y;
          v3 = v[i][1 + j + 10]  + pv.z;
          v4 = v[i][1 + j + 15]  + pv.w;
        }
        na[j] = lse5(v0, v1, v2, v3, v4);
      }

      // refill this pipeline slot (consumed 4 steps from now)
      if (step + 4 < T_STEPS) prefetch<DIR>(base, step + 4, u, v[i], s5[i]);

      if (DIR == 0) {
        const float4 o = {na[0], na[1], na[2], na[3]};
        ((float4*)(outn + (size_t)(step + 1) * SST))[u] = o;
        *(float4*)&abuf[nxt][4 * u] = o;
      } else {
        const int t = T_STEPS - 1 - step;
#pragma unroll
        for (int j = 0; j < 4; ++j) {
          outn[(size_t)t * SST + u + 256 * j] = na[j];
          abuf[nxt][u + 256 * j] = na[j];
        }
      }
#pragma unroll
      for (int j = 0; j < 4; ++j) a[j] = na[j];

      sync_lds();
    }
  }
}

__global__ __launch_bounds__(256) void mega(const float* __restrict__ scores,
                                            float* __restrict__ out0,
                                            float* __restrict__ bwdo,
                                            float* __restrict__ fposts) {
  __shared__ float abuf[2][SST];
  const int b = blockIdx.x;
  if (b < SCAN_BLOCKS) {
    if (b < NBATCH) scan_run<0>(scores, fposts, b, abuf);
    else            scan_run<1>(scores, bwdo,   b - NBATCH, abuf);
  } else {
    // transpose-copy: out0[n][t][:] = scores[t][n][:], row-contiguous both sides
    const int tb = b - SCAN_BLOCKS;
    for (int r = tb; r < NBATCH * T_STEPS; r += COPY_BLOCKS) {
      const int t = r / NBATCH, n = r % NBATCH;
      const float4* src = (const float4*)(scores + (size_t)r * ROW);
      float4* dst = (float4*)(out0 + ((size_t)n * T_STEPS + t) * ROW);
#pragma unroll
      for (int i = 0; i < 5; ++i)
        dst[threadIdx.x + 256 * i] = src[threadIdx.x + 256 * i];
    }
  }
}

// One wave per row of 1024: posts = softmax(fwd + bwd), in place over fwd buffer.
__global__ __launch_bounds__(256) void posts_kernel(float* __restrict__ fp,
                                                    const float* __restrict__ bp) {
  const int lane = threadIdx.x & 63;
  const int wid  = threadIdx.x >> 6;
  const size_t row = (size_t)blockIdx.x * 4 + wid;
  float* f = fp + row * SST;
  const float* b = bp + row * SST;

  float x[16];
#pragma unroll
  for (int k = 0; k < 4; ++k) {
    const float4 fv = ((const float4*)f)[lane + 64 * k];
    const float4 bv = ((const float4*)b)[lane + 64 * k];
    x[4 * k + 0] = fv.x + bv.x;
    x[4 * k + 1] = fv.y + bv.y;
    x[4 * k + 2] = fv.z + bv.z;
    x[4 * k + 3] = fv.w + bv.w;
  }
  float m = x[0];
#pragma unroll
  for (int j = 1; j < 16; ++j) m = fmaxf(m, x[j]);
#pragma unroll
  for (int off = 32; off >= 1; off >>= 1) m = fmaxf(m, __shfl_xor(m, off));
  float ssum = 0.0f;
#pragma unroll
  for (int j = 0; j < 16; ++j) { x[j] = __expf(x[j] - m); ssum += x[j]; }
#pragma unroll
  for (int off = 32; off >= 1; off >>= 1) ssum += __shfl_xor(ssum, off);
  const float inv = 1.0f / ssum;
#pragma unroll
  for (int k = 0; k < 4; ++k) {
    float4 o;
    o.x = x[4 * k + 0] * inv;
    o.y = x[4 * k + 1] * inv;
    o.z = x[4 * k + 2] * inv;
    o.w = x[4 * k + 3] * inv;
    ((float4*)f)[lane + 64 * k] = o;
  }
}

extern "C" void kernel_launch(void* const* d_in, const int* in_sizes, int n_in,
                              void* d_out, int out_size, void* d_ws, size_t ws_size,
                              hipStream_t stream) {
  (void)in_sizes; (void)n_in; (void)d_ws; (void)ws_size; (void)out_size;
  const float* scores = (const float*)d_in[0];
  float* out = (float*)d_out;
  float* out0   = out;                                                  // (32,800,5120)
  float* bwdo   = out + (size_t)NBATCH * T_STEPS * ROW;                 // (32,801,1024)
  float* fposts = bwdo + (size_t)NBATCH * (T_STEPS + 1) * SST;          // (32,801,1024)

  mega<<<GRID, 256, 0, stream>>>(scores, out0, bwdo, fposts);
  posts_kernel<<<(NBATCH * (T_STEPS + 1)) / 4, 256, 0, stream>>>(fposts, bwdo);
}

// Round 4
// 820.732 us; speedup vs baseline: 1.0159x; 1.0159x over previous
//
#include <hip/hip_runtime.h>

#define T_STEPS 800
#define NBATCH  32
#define SST     1024
#define ROW     5120   // SST * 5
#define DEPTH   8      // register prefetch pipeline depth (800 % 8 == 0)

#define SCAN_BLOCKS 64
#define COPY_BLOCKS 1536
#define GRID (SCAN_BLOCKS + COPY_BLOCKS)

__device__ __forceinline__ float lse5(float v0, float v1, float v2, float v3, float v4) {
  float m = fmaxf(fmaxf(fmaxf(v0, v1), fmaxf(v2, v3)), v4);
  float s = __expf(v0 - m) + __expf(v1 - m) + __expf(v2 - m) +
            __expf(v3 - m) + __expf(v4 - m);
  return m + __logf(s);
}

// Raw barrier: LDS fence only, leaves global prefetch (vmcnt) in flight.
__device__ __forceinline__ void sync_lds() {
  asm volatile("s_waitcnt lgkmcnt(0)" ::: "memory");
  __builtin_amdgcn_s_barrier();
  asm volatile("" ::: "memory");
}

// Per-thread score prefetch for one step: 20 contiguous floats at 20u
// (5x dwordx4), plus (bwd only) the 4 scattered self-scores.
template <int DIR>
__device__ __forceinline__ void prefetch(const float* __restrict__ base, int step, int u,
                                         float* __restrict__ r, float* __restrict__ s) {
  const int t = DIR ? (T_STEPS - 1 - step) : step;
  const float* rp = base + (size_t)t * (NBATCH * ROW);
#pragma unroll
  for (int m = 0; m < 5; ++m)
    *(float4*)&r[4 * m] = *(const float4*)&rp[20 * u + 4 * m];
  if (DIR) {
#pragma unroll
    for (int j = 0; j < 4; ++j) s[j] = rp[5 * u + 1280 * j];
  }
}

// DIR=0 (fwd): thread u owns states {4u..4u+3}. Gather: abuf[u + 256k].
// DIR=1 (bwd): thread u owns states {u + 256j}. Gather: abuf[4u..4u+3].
template <int DIR>
__device__ void scan_run(const float* __restrict__ scores, float* __restrict__ out,
                         int n, float (*abuf)[SST]) {
  const int u = threadIdx.x;  // 0..255
  const float* base = scores + (size_t)n * ROW;
  float* outn = out + (size_t)n * (T_STEPS + 1) * SST;

  float a[4] = {0.f, 0.f, 0.f, 0.f};  // own states' alpha/beta (self-edge operand)

  // DEPTH-deep register prefetch pipeline (steps 0..DEPTH-1)
  float v[DEPTH][20];
  float s5[DEPTH][4];
#pragma unroll
  for (int i = 0; i < DEPTH; ++i) prefetch<DIR>(base, i, u, v[i], s5[i]);

  // init alpha[0]=0 / beta[T]=0 in LDS and in the output
  abuf[0][u] = 0.f; abuf[0][u + 256] = 0.f; abuf[0][u + 512] = 0.f; abuf[0][u + 768] = 0.f;
  {
    const float4 z = {0.f, 0.f, 0.f, 0.f};
    const size_t t0 = DIR ? (size_t)T_STEPS : 0;
    ((float4*)(outn + t0 * SST))[u] = z;
  }
  sync_lds();

  for (int p = 0; p < T_STEPS; p += DEPTH) {
#pragma unroll
    for (int i = 0; i < DEPTH; ++i) {
      const int step = p + i;
      const int cur = step & 1;
      const int nxt = cur ^ 1;

      float4 pv;
      if (DIR == 0) {
        pv.x = abuf[cur][u];
        pv.y = abuf[cur][u + 256];
        pv.z = abuf[cur][u + 512];
        pv.w = abuf[cur][u + 768];
      } else {
        pv = *(const float4*)&abuf[cur][4 * u];
      }

      float na[4];
#pragma unroll
      for (int j = 0; j < 4; ++j) {
        float v0, v1, v2, v3, v4;
        if (DIR == 0) {
          // state 4u+j: its 5 scores are flat [5j..5j+4] of this thread's 20
          v0 = v[i][5 * j + 0] + a[j];
          v1 = v[i][5 * j + 1] + pv.x;
          v2 = v[i][5 * j + 2] + pv.y;
          v3 = v[i][5 * j + 3] + pv.z;
          v4 = v[i][5 * j + 4] + pv.w;
        } else {
          // state u+256j: self score scattered; trans scores at flat 1+j+5m
          v0 = s5[i][j]          + a[j];
          v1 = v[i][1 + j + 0]   + pv.x;
          v2 = v[i][1 + j + 5]   + pv.y;
          v3 = v[i][1 + j + 10]  + pv.z;
          v4 = v[i][1 + j + 15]  + pv.w;
        }
        na[j] = lse5(v0, v1, v2, v3, v4);
      }

      // refill this pipeline slot (consumed DEPTH steps from now)
      if (step + DEPTH < T_STEPS) prefetch<DIR>(base, step + DEPTH, u, v[i], s5[i]);

      if (DIR == 0) {
        const float4 o = {na[0], na[1], na[2], na[3]};
        ((float4*)(outn + (size_t)(step + 1) * SST))[u] = o;
        *(float4*)&abuf[nxt][4 * u] = o;
      } else {
        const int t = T_STEPS - 1 - step;
#pragma unroll
        for (int j = 0; j < 4; ++j) {
          outn[(size_t)t * SST + u + 256 * j] = na[j];
          abuf[nxt][u + 256 * j] = na[j];
        }
      }
#pragma unroll
      for (int j = 0; j < 4; ++j) a[j] = na[j];

      sync_lds();
    }
  }
}

__global__ __launch_bounds__(256, 1) void mega(const float* __restrict__ scores,
                                               float* __restrict__ out0,
                                               float* __restrict__ bwdo,
                                               float* __restrict__ fposts) {
  __shared__ float abuf[2][SST];
  const int b = blockIdx.x;
  if (b < SCAN_BLOCKS) {
    if (b < NBATCH) scan_run<0>(scores, fposts, b, abuf);
    else            scan_run<1>(scores, bwdo,   b - NBATCH, abuf);
  } else {
    // transpose-copy: out0[n][t][:] = scores[t][n][:], row-contiguous both sides
    const int tb = b - SCAN_BLOCKS;
    for (int r = tb; r < NBATCH * T_STEPS; r += COPY_BLOCKS) {
      const int t = r / NBATCH, n = r % NBATCH;
      const float4* src = (const float4*)(scores + (size_t)r * ROW);
      float4* dst = (float4*)(out0 + ((size_t)n * T_STEPS + t) * ROW);
#pragma unroll
      for (int i = 0; i < 5; ++i)
        dst[threadIdx.x + 256 * i] = src[threadIdx.x + 256 * i];
    }
  }
}

// One wave per row of 1024: posts = softmax(fwd + bwd), in place over fwd buffer.
__global__ __launch_bounds__(256) void posts_kernel(float* __restrict__ fp,
                                                    const float* __restrict__ bp) {
  const int lane = threadIdx.x & 63;
  const int wid  = threadIdx.x >> 6;
  const size_t row = (size_t)blockIdx.x * 4 + wid;
  float* f = fp + row * SST;
  const float* b = bp + row * SST;

  float x[16];
#pragma unroll
  for (int k = 0; k < 4; ++k) {
    const float4 fv = ((const float4*)f)[lane + 64 * k];
    const float4 bv = ((const float4*)b)[lane + 64 * k];
    x[4 * k + 0] = fv.x + bv.x;
    x[4 * k + 1] = fv.y + bv.y;
    x[4 * k + 2] = fv.z + bv.z;
    x[4 * k + 3] = fv.w + bv.w;
  }
  float m = x[0];
#pragma unroll
  for (int j = 1; j < 16; ++j) m = fmaxf(m, x[j]);
#pragma unroll
  for (int off = 32; off >= 1; off >>= 1) m = fmaxf(m, __shfl_xor(m, off));
  float ssum = 0.0f;
#pragma unroll
  for (int j = 0; j < 16; ++j) { x[j] = __expf(x[j] - m); ssum += x[j]; }
#pragma unroll
  for (int off = 32; off >= 1; off >>= 1) ssum += __shfl_xor(ssum, off);
  const float inv = 1.0f / ssum;
#pragma unroll
  for (int k = 0; k < 4; ++k) {
    float4 o;
    o.x = x[4 * k + 0] * inv;
    o.y = x[4 * k + 1] * inv;
    o.z = x[4 * k + 2] * inv;
    o.w = x[4 * k + 3] * inv;
    ((float4*)f)[lane + 64 * k] = o;
  }
}

extern "C" void kernel_launch(void* const* d_in, const int* in_sizes, int n_in,
                              void* d_out, int out_size, void* d_ws, size_t ws_size,
                              hipStream_t stream) {
  (void)in_sizes; (void)n_in; (void)d_ws; (void)ws_size; (void)out_size;
  const float* scores = (const float*)d_in[0];
  float* out = (float*)d_out;
  float* out0   = out;                                                  // (32,800,5120)
  float* bwdo   = out + (size_t)NBATCH * T_STEPS * ROW;                 // (32,801,1024)
  float* fposts = bwdo + (size_t)NBATCH * (T_STEPS + 1) * SST;          // (32,801,1024)

  mega<<<GRID, 256, 0, stream>>>(scores, out0, bwdo, fposts);
  posts_kernel<<<(NBATCH * (T_STEPS + 1)) / 4, 256, 0, stream>>>(fposts, bwdo);
}

// Round 7
// 694.129 us; speedup vs baseline: 1.2012x; 1.1824x over previous
//
#include <hip/hip_runtime.h>
#include <stdint.h>

#define T_STEPS 800
#define NBATCH  32
#define SST     1024
#define ROW     5120   // SST * 5 floats per (t, n) row
#define RING    5      // LDS ring depth (rows in flight); 800 % 5 == 0

#define SCAN_BLOCKS 64
#define COPY_BLOCKS 1536
#define GRID (SCAN_BLOCKS + COPY_BLOCKS)

__device__ __forceinline__ float lse5(float v0, float v1, float v2, float v3, float v4) {
  float m = fmaxf(fmaxf(fmaxf(v0, v1), fmaxf(v2, v3)), v4);
  float s = __expf(v0 - m) + __expf(v1 - m) + __expf(v2 - m) +
            __expf(v3 - m) + __expf(v4 - m);
  return m + __logf(s);
}

// Counted vmcnt wait + scheduling fence (rule #18).
#define WAITVM(N) do { \
  asm volatile("s_waitcnt vmcnt(" #N ")" ::: "memory"); \
  __builtin_amdgcn_sched_barrier(0); } while (0)

// Block barrier that drains LDS ops but leaves global (vmcnt) traffic in flight.
__device__ __forceinline__ void barrier_lgkm() {
  asm volatile("s_waitcnt lgkmcnt(0)" ::: "memory");
  __builtin_amdgcn_s_barrier();
  asm volatile("" ::: "memory");
}

// Async DMA global->LDS, 16B per lane. No register result => compiler cannot
// sink it to the use site; completion is tracked by OUR counted vmcnt.
__device__ __forceinline__ void stage16(const float* g, float* l) {
  __builtin_amdgcn_global_load_lds(
      (const __attribute__((address_space(1))) uint32_t*)g,
      (__attribute__((address_space(3))) uint32_t*)l, 16, 0, 0);
}

// Wave w stages its own 5 KB quarter of a 20 KB row: floats [1280w, 1280w+1280).
// LDS dest is wave-uniform base; HW writes base + lane*16B, matching the
// per-lane global src (+4*lane floats). 5 vmcnt ops per wave per row.
__device__ __forceinline__ void stage_row(const float* __restrict__ rowg,
                                          float* __restrict__ ldsrow,
                                          int w, int lane) {
  const float* src = rowg + 1280 * w + 4 * lane;
  float* dst = ldsrow + 1280 * w;
#pragma unroll
  for (int k = 0; k < 5; ++k) stage16(src + 256 * k, dst + 256 * k);
}

// Per-step vmcnt accounting (per wave, ops in order [ST stores][5 stage]):
//   steady  N = (RING-1)*(5+ST):  fwd ST=1 -> 24, bwd ST=4 -> 36
//   prologue N = (RING-1)*5 + 1 = 21 (exact at s=0, slight over-wait after)
//   tail     N = 0 (drain; last RING steps only)
// PHASE: 0=prologue, 1=steady, 2=tail (no restage).
template <int DIR, int PHASE>
__device__ __forceinline__ void step_one(int s, int buf, int u, int w, int lane,
                                         const float* __restrict__ base,
                                         float* __restrict__ outn,
                                         float (*ring)[ROW], float (*abuf)[SST],
                                         float (&a)[4]) {
  // A: own-wave staging of row s complete.
  if constexpr (PHASE == 0)      WAITVM(21);
  else if constexpr (PHASE == 1) { if constexpr (DIR) WAITVM(36); else WAITVM(24); }
  else                           WAITVM(0);

  // B: bwd reads self-scores from other waves' row regions -> must see ALL
  // waves' staging landed (each wave certified its own via A; barrier joins).
  // fwd reads only its own wave's region + abuf (published by prev bar2).
  if constexpr (DIR) barrier_lgkm();

  const int cur = s & 1;
  const int nxt = cur ^ 1;
  const float* rb = ring[buf];

  // C: consume scores from LDS (5x ds_read_b128, conflict-minimal layout).
  float4 q[5];
  const float4* rv = (const float4*)(rb + 20 * u);
#pragma unroll
  for (int m = 0; m < 5; ++m) q[m] = rv[m];
  float fv[20];
#pragma unroll
  for (int m = 0; m < 5; ++m) {
    fv[4 * m + 0] = q[m].x; fv[4 * m + 1] = q[m].y;
    fv[4 * m + 2] = q[m].z; fv[4 * m + 3] = q[m].w;
  }
  float sv[4];
  if constexpr (DIR) {
#pragma unroll
    for (int j = 0; j < 4; ++j) sv[j] = rb[5 * u + 1280 * j];
  }

  float4 pv;
  if constexpr (!DIR) {
    pv.x = abuf[cur][u];
    pv.y = abuf[cur][u + 256];
    pv.z = abuf[cur][u + 512];
    pv.w = abuf[cur][u + 768];
  } else {
    pv = *(const float4*)&abuf[cur][4 * u];
  }

  // D: compute (identical recurrence to the R4-validated kernel).
  float na[4];
#pragma unroll
  for (int j = 0; j < 4; ++j) {
    float w0, w1, w2, w3, w4;
    if constexpr (!DIR) {
      w0 = fv[5 * j + 0] + a[j];
      w1 = fv[5 * j + 1] + pv.x;
      w2 = fv[5 * j + 2] + pv.y;
      w3 = fv[5 * j + 3] + pv.z;
      w4 = fv[5 * j + 4] + pv.w;
    } else {
      w0 = sv[j]          + a[j];
      w1 = fv[1 + j + 0]  + pv.x;
      w2 = fv[1 + j + 5]  + pv.y;
      w3 = fv[1 + j + 10] + pv.z;
      w4 = fv[1 + j + 15] + pv.w;
    }
    na[j] = lse5(w0, w1, w2, w3, w4);
    a[j] = na[j];
  }

  // E/F: global store (ST vm ops) + abuf publish (LDS).
  if constexpr (!DIR) {
    const float4 o = {na[0], na[1], na[2], na[3]};
    ((float4*)(outn + (size_t)(s + 1) * SST))[u] = o;   // ST = 1
    *(float4*)&abuf[nxt][4 * u] = o;
  } else {
    const int t = T_STEPS - 1 - s;
#pragma unroll
    for (int j = 0; j < 4; ++j) {
      outn[(size_t)t * SST + u + 256 * j] = na[j];       // ST = 4
      abuf[nxt][u + 256 * j] = na[j];
    }
  }

  // bar2: all waves' reads of ring[buf] done (safe to restage) + abuf visible.
  barrier_lgkm();

  // H: restage this buffer with row s+RING (5 vm ops; no reg result).
  if constexpr (PHASE != 2) {
    const int tn = DIR ? (T_STEPS - 1 - (s + RING)) : (s + RING);
    stage_row(base + (size_t)tn * (NBATCH * ROW), ring[buf], w, lane);
  }
}

// DIR=0 (fwd): thread u owns states {4u..4u+3}; gathers abuf[u+256k].
// DIR=1 (bwd): thread u owns states {u+256j}; gathers abuf[4u..4u+3].
template <int DIR>
__device__ void scan_run(const float* __restrict__ scores, float* __restrict__ out,
                         int n, float (*ring)[ROW], float (*abuf)[SST]) {
  const int u = threadIdx.x;       // 0..255
  const int w = u >> 6, lane = u & 63;
  const float* base = scores + (size_t)n * ROW;
  float* outn = out + (size_t)n * (T_STEPS + 1) * SST;
  float a[4] = {0.f, 0.f, 0.f, 0.f};

  // Prologue staging: rows 0..RING-1 (25 vm ops/wave, in row order).
#pragma unroll
  for (int i = 0; i < RING; ++i) {
    const int t = DIR ? (T_STEPS - 1 - i) : i;
    stage_row(base + (size_t)t * (NBATCH * ROW), ring[i], w, lane);
  }
  // Init alpha[0]/beta[T] = 0 (after stages: exactly 1 newer vm store).
  {
    const float4 z = {0.f, 0.f, 0.f, 0.f};
    *(float4*)&abuf[0][4 * u] = z;
    const size_t t0 = DIR ? (size_t)T_STEPS : 0;
    ((float4*)(outn + t0 * SST))[u] = z;
  }
  barrier_lgkm();  // abuf[0] visible block-wide

#pragma unroll
  for (int i = 0; i < RING; ++i)
    step_one<DIR, 0>(i, i, u, w, lane, base, outn, ring, abuf, a);

  for (int p = RING; p < T_STEPS - RING; p += RING) {
#pragma unroll
    for (int i = 0; i < RING; ++i)
      step_one<DIR, 1>(p + i, i, u, w, lane, base, outn, ring, abuf, a);
  }

#pragma unroll
  for (int i = 0; i < RING; ++i)
    step_one<DIR, 2>(T_STEPS - RING + i, i, u, w, lane, base, outn, ring, abuf, a);
}

__global__ __launch_bounds__(256) void mega(const float* __restrict__ scores,
                                            float* __restrict__ out0,
                                            float* __restrict__ bwdo,
                                            float* __restrict__ fposts) {
  __shared__ float ring[RING][ROW];   // 100 KB score ring
  __shared__ float abuf[2][SST];      // 8 KB alpha exchange
  const int b = blockIdx.x;
  if (b < SCAN_BLOCKS) {
    if (b < NBATCH) scan_run<0>(scores, fposts, b, ring, abuf);
    else            scan_run<1>(scores, bwdo,   b - NBATCH, ring, abuf);
  } else {
    // transpose-copy: out0[n][t][:] = scores[t][n][:], row-contiguous both sides
    const int tb = b - SCAN_BLOCKS;
    for (int r = tb; r < NBATCH * T_STEPS; r += COPY_BLOCKS) {
      const int t = r / NBATCH, n = r % NBATCH;
      const float4* src = (const float4*)(scores + (size_t)r * ROW);
      float4* dst = (float4*)(out0 + ((size_t)n * T_STEPS + t) * ROW);
#pragma unroll
      for (int i = 0; i < 5; ++i)
        dst[threadIdx.x + 256 * i] = src[threadIdx.x + 256 * i];
    }
  }
}

// One wave per row of 1024: posts = softmax(fwd + bwd), in place over fwd buffer.
__global__ __launch_bounds__(256) void posts_kernel(float* __restrict__ fp,
                                                    const float* __restrict__ bp) {
  const int lane = threadIdx.x & 63;
  const int wid  = threadIdx.x >> 6;
  const size_t row = (size_t)blockIdx.x * 4 + wid;
  float* f = fp + row * SST;
  const float* b = bp + row * SST;

  float x[16];
#pragma unroll
  for (int k = 0; k < 4; ++k) {
    const float4 fv = ((const float4*)f)[lane + 64 * k];
    const float4 bv = ((const float4*)b)[lane + 64 * k];
    x[4 * k + 0] = fv.x + bv.x;
    x[4 * k + 1] = fv.y + bv.y;
    x[4 * k + 2] = fv.z + bv.z;
    x[4 * k + 3] = fv.w + bv.w;
  }
  float m = x[0];
#pragma unroll
  for (int j = 1; j < 16; ++j) m = fmaxf(m, x[j]);
#pragma unroll
  for (int off = 32; off >= 1; off >>= 1) m = fmaxf(m, __shfl_xor(m, off));
  float ssum = 0.0f;
#pragma unroll
  for (int j = 0; j < 16; ++j) { x[j] = __expf(x[j] - m); ssum += x[j]; }
#pragma unroll
  for (int off = 32; off >= 1; off >>= 1) ssum += __shfl_xor(ssum, off);
  const float inv = 1.0f / ssum;
#pragma unroll
  for (int k = 0; k < 4; ++k) {
    float4 o;
    o.x = x[4 * k + 0] * inv;
    o.y = x[4 * k + 1] * inv;
    o.z = x[4 * k + 2] * inv;
    o.w = x[4 * k + 3] * inv;
    ((float4*)f)[lane + 64 * k] = o;
  }
}

extern "C" void kernel_launch(void* const* d_in, const int* in_sizes, int n_in,
                              void* d_out, int out_size, void* d_ws, size_t ws_size,
                              hipStream_t stream) {
  (void)in_sizes; (void)n_in; (void)d_ws; (void)ws_size; (void)out_size;
  const float* scores = (const float*)d_in[0];
  float* out = (float*)d_out;
  float* out0   = out;                                                  // (32,800,5120)
  float* bwdo   = out + (size_t)NBATCH * T_STEPS * ROW;                 // (32,801,1024)
  float* fposts = bwdo + (size_t)NBATCH * (T_STEPS + 1) * SST;          // (32,801,1024)

  mega<<<GRID, 256, 0, stream>>>(scores, out0, bwdo, fposts);
  posts_kernel<<<(NBATCH * (T_STEPS + 1)) / 4, 256, 0, stream>>>(fposts, bwdo);
}